// Round 3
// baseline (839.392 us; speedup 1.0000x reference)
//
#include <hip/hip_runtime.h>

// EmbedLoopyBP on gfx950 — round 3.
// All edge arrays in CSR(dst)-slot order: imP, srcP, prevP, curP*. k_iter is
// barrier-free/LDS-free: A = Wc^T frags in registers, B = x frags built in
// registers; D[n][m] lands col=edge-row so each lane stores contiguous 8B.
// Only remaining gather: cinP[prevP[slot]] (bijective, 128B rows). naW in bf16.
// k_seg: 8 lanes x 8 rows per 1KB load instruction + shfl_xor reduce.

#define NN 50000
#define NE 800000
#define NG 128
#define D 64
#define GPW 4

typedef unsigned short u16;
typedef unsigned int u32;
typedef __bf16 bf16x8 __attribute__((ext_vector_type(8)));
typedef float f32x4 __attribute__((ext_vector_type(4)));

union BF8 { u16 u[8]; bf16x8 b; };

__device__ __forceinline__ float b2f(u16 u){ u32 x=((u32)u)<<16; float f; __builtin_memcpy(&f,&x,4); return f; }
__device__ __forceinline__ u16 f2b(float f){ u32 x; __builtin_memcpy(&x,&f,4); x += 0x7fffu + ((x>>16)&1u); return (u16)(x>>16); }
__device__ __forceinline__ u32 pack2(float a, float b){ return (u32)f2b(a) | ((u32)f2b(b)<<16); }
__device__ __forceinline__ void unpack8(uint4 v, float* o){
  o[0]=b2f((u16)(v.x&0xffffu)); o[1]=b2f((u16)(v.x>>16));
  o[2]=b2f((u16)(v.y&0xffffu)); o[3]=b2f((u16)(v.y>>16));
  o[4]=b2f((u16)(v.z&0xffffu)); o[5]=b2f((u16)(v.z>>16));
  o[6]=b2f((u16)(v.w&0xffffu)); o[7]=b2f((u16)(v.w>>16));
}
__device__ __forceinline__ bf16x8 asbf(uint4 v){ bf16x8 r; __builtin_memcpy(&r,&v,16); return r; }

// ---------------- node linear: inl = node_feat @ Wn + bn (fp32) ----------------
__global__ __launch_bounds__(256) void k_inl(const float* __restrict__ nf, const float* __restrict__ Wn,
                                             const float* __restrict__ bn, float* __restrict__ inl){
  __shared__ float w[D*D];
  for (int i=threadIdx.x;i<D*D;i+=256) w[i]=Wn[i];
  __syncthreads();
  const int d = threadIdx.x&63;
  const int n = blockIdx.x*4 + (threadIdx.x>>6);
  if (n>=NN) return;
  float v = bn[d];
  const float* row = nf + (size_t)n*D;
  #pragma unroll 8
  for (int k=0;k<D;k++) v += row[k]*w[k*D+d];
  inl[(size_t)n*D+d] = v;
}

// ---------------- imP[perm[e]] = edge_feat@We + be + inl[src[e]]  (bf16) ----------------
__global__ __launch_bounds__(256) void k_im(const float* __restrict__ ef, const float* __restrict__ We,
                                            const float* __restrict__ be, const float* __restrict__ inl,
                                            const int* __restrict__ src, const int* __restrict__ perm,
                                            u16* __restrict__ imP){
  const int t = threadIdx.x;
  const int lane = t&63, m = lane&15, q = lane>>4;
  const int wgid = blockIdx.x*4 + (t>>6);
  bf16x8 Wf[4];                       // A-frags: We^T rows (n), K=32
  #pragma unroll
  for (int nt=0;nt<4;nt++){
    BF8 a;
    #pragma unroll
    for (int j=0;j<8;j++) a.u[j] = f2b(We[(q*8+j)*D + nt*16 + m]);
    Wf[nt]=a.b;
  }
  float4 be4[4];
  #pragma unroll
  for (int nt=0;nt<4;nt++) be4[nt] = *(const float4*)(be + nt*16 + q*4);
  for (int gi=0; gi<GPW; gi++){
    const int e = (wgid*GPW+gi)*16 + m;
    const float* ep = ef + (size_t)e*32 + q*8;
    float4 f0 = *(const float4*)ep, f1 = *(const float4*)(ep+4);
    uint4 bp = make_uint4(pack2(f0.x,f0.y),pack2(f0.z,f0.w),pack2(f1.x,f1.y),pack2(f1.z,f1.w));
    bf16x8 B = asbf(bp);
    const int s = src[e], ps = perm[e];
    const float* ip = inl + (size_t)s*D;
    u16* op = imP + (size_t)ps*D;
    #pragma unroll
    for (int nt=0;nt<4;nt++){
      f32x4 acc = {0.f,0.f,0.f,0.f};
      acc = __builtin_amdgcn_mfma_f32_16x16x32_bf16(Wf[nt], B, acc, 0,0,0);
      float4 il = *(const float4*)(ip + nt*16 + q*4);
      float v0=acc[0]+be4[nt].x+il.x, v1=acc[1]+be4[nt].y+il.y;
      float v2=acc[2]+be4[nt].z+il.z, v3=acc[3]+be4[nt].w+il.w;
      *(uint2*)(op + nt*16 + q*4) = make_uint2(pack2(v0,v1), pack2(v2,v3));
    }
  }
}

// ---------------- iteration kernel (slot-ordered, barrier-free) ----------------
// MODE 0: x=relu(imP[slot]);                                  outP[slot]=(x@Wc)
// MODE 1: x=relu(naWb[srcP]-cinP[prevP]+bc+imP[slot]);        outP[slot]=(x@Wc)
// MODE 2: x=relu(naWb[srcP]-cinP[prevP]+bc+imP[slot]);        outP[slot]=x
template<int MODE>
__global__ __launch_bounds__(256) void k_iter(const u16* __restrict__ imP, const u16* __restrict__ cinP,
      const u16* __restrict__ naWb, const float* __restrict__ Wc, const float* __restrict__ bc,
      const int* __restrict__ srcP, const int* __restrict__ prevP, u16* __restrict__ outP){
  const int t = threadIdx.x;
  const int lane = t&63, m = lane&15, q = lane>>4;
  const int wgid = blockIdx.x*4 + (t>>6);
  bf16x8 Af[2][4];                    // A-frags: Wc^T rows (n), K=64 -> 2 ksteps
  if (MODE != 2){
    #pragma unroll
    for (int ks=0;ks<2;ks++)
      #pragma unroll
      for (int nt=0;nt<4;nt++){
        BF8 a;
        #pragma unroll
        for (int j=0;j<8;j++) a.u[j] = f2b(Wc[(ks*32 + q*8 + j)*D + nt*16 + m]);
        Af[ks][nt]=a.b;
      }
  }
  float bc0[8], bc1[8];
  if (MODE != 0){
    float4 a0=*(const float4*)(bc+q*8),    a1=*(const float4*)(bc+q*8+4);
    float4 a2=*(const float4*)(bc+32+q*8), a3=*(const float4*)(bc+32+q*8+4);
    bc0[0]=a0.x;bc0[1]=a0.y;bc0[2]=a0.z;bc0[3]=a0.w;bc0[4]=a1.x;bc0[5]=a1.y;bc0[6]=a1.z;bc0[7]=a1.w;
    bc1[0]=a2.x;bc1[1]=a2.y;bc1[2]=a2.z;bc1[3]=a2.w;bc1[4]=a3.x;bc1[5]=a3.y;bc1[6]=a3.z;bc1[7]=a3.w;
  }
  for (int gi=0; gi<GPW; gi++){
    const int slot = (wgid*GPW+gi)*16 + m;
    const u16* ip = imP + (size_t)slot*D;
    uint4 i0 = *(const uint4*)(ip + q*8);
    uint4 i1 = *(const uint4*)(ip + 32 + q*8);
    float x0[8], x1[8];
    unpack8(i0,x0); unpack8(i1,x1);
    if (MODE != 0){
      const int pv = prevP[slot], sp = srcP[slot];
      const u16* cp  = cinP + (size_t)pv*D;
      const u16* np_ = naWb + (size_t)sp*D;
      uint4 c0 = *(const uint4*)(cp + q*8),  c1 = *(const uint4*)(cp + 32 + q*8);
      uint4 n0 = *(const uint4*)(np_ + q*8), n1 = *(const uint4*)(np_ + 32 + q*8);
      float cv[8], nv[8];
      unpack8(c0,cv); unpack8(n0,nv);
      #pragma unroll
      for (int j=0;j<8;j++) x0[j] += nv[j] - cv[j] + bc0[j];
      unpack8(c1,cv); unpack8(n1,nv);
      #pragma unroll
      for (int j=0;j<8;j++) x1[j] += nv[j] - cv[j] + bc1[j];
    }
    #pragma unroll
    for (int j=0;j<8;j++){ x0[j] = x0[j]>0.f?x0[j]:0.f; x1[j] = x1[j]>0.f?x1[j]:0.f; }
    uint4 p0 = make_uint4(pack2(x0[0],x0[1]),pack2(x0[2],x0[3]),pack2(x0[4],x0[5]),pack2(x0[6],x0[7]));
    uint4 p1 = make_uint4(pack2(x1[0],x1[1]),pack2(x1[2],x1[3]),pack2(x1[4],x1[5]),pack2(x1[6],x1[7]));
    u16* op = outP + (size_t)slot*D;
    if (MODE == 2){
      *(uint4*)(op + q*8) = p0; *(uint4*)(op + 32 + q*8) = p1;
    } else {
      bf16x8 B0 = asbf(p0), B1 = asbf(p1);
      #pragma unroll
      for (int nt=0;nt<4;nt++){
        f32x4 acc = {0.f,0.f,0.f,0.f};
        acc = __builtin_amdgcn_mfma_f32_16x16x32_bf16(Af[0][nt], B0, acc, 0,0,0);
        acc = __builtin_amdgcn_mfma_f32_16x16x32_bf16(Af[1][nt], B1, acc, 0,0,0);
        *(uint2*)(op + nt*16 + q*4) = make_uint2(pack2(acc[0],acc[1]), pack2(acc[2],acc[3]));
      }
    }
  }
}

// ---------------- streaming segment sum -> bf16 node rows ----------------
__global__ __launch_bounds__(256) void k_seg(const u16* __restrict__ curP, const int* __restrict__ off,
                                             u16* __restrict__ outb){
  const int n = blockIdx.x*4 + (threadIdx.x>>6);
  const int lane = threadIdx.x&63, rg = lane>>3, c8 = lane&7;
  if (n>=NN) return;
  const int p0=off[n], p1=off[n+1];
  float s[8] = {0.f,0.f,0.f,0.f,0.f,0.f,0.f,0.f};
  for (int p = p0+rg; p < p1; p += 8){
    uint4 v = *(const uint4*)(curP + (size_t)p*D + c8*8);
    float tv[8]; unpack8(v,tv);
    #pragma unroll
    for (int j=0;j<8;j++) s[j]+=tv[j];
  }
  #pragma unroll
  for (int j=0;j<8;j++) s[j] += __shfl_xor(s[j], 8, 64);
  #pragma unroll
  for (int j=0;j<8;j++) s[j] += __shfl_xor(s[j], 16, 64);
  #pragma unroll
  for (int j=0;j<8;j++) s[j] += __shfl_xor(s[j], 32, 64);
  if (rg==0){
    uint4 o = make_uint4(pack2(s[0],s[1]),pack2(s[2],s[3]),pack2(s[4],s[5]),pack2(s[6],s[7]));
    *(uint4*)(outb + (size_t)n*D + c8*8) = o;
  }
}

// ---------------- CSR build ----------------
__global__ void k_hist(const int* __restrict__ dst, int* __restrict__ cnt){
  int e = blockIdx.x*256 + threadIdx.x;
  atomicAdd(&cnt[dst[e]], 1);
}
__global__ __launch_bounds__(1024) void k_scan1(const int* __restrict__ cnt, int* __restrict__ outv,
                                                int* __restrict__ bsums, int n){
  __shared__ int sh[1024];
  int i = blockIdx.x*1024 + threadIdx.x;
  int v = (i<n)? cnt[i] : 0;
  sh[threadIdx.x]=v;
  __syncthreads();
  for (int off=1; off<1024; off<<=1){
    int tv = (threadIdx.x>=(unsigned)off)? sh[threadIdx.x-off] : 0;
    __syncthreads();
    sh[threadIdx.x] += tv;
    __syncthreads();
  }
  if (i<n) outv[i] = sh[threadIdx.x] - v;
  if (threadIdx.x==1023) bsums[blockIdx.x] = sh[1023];
}
__global__ void k_scan2(int* bsums, int nb, int* tot){
  if (threadIdx.x==0 && blockIdx.x==0){
    int run=0;
    for (int b=0;b<nb;b++){ int v=bsums[b]; bsums[b]=run; run+=v; }
    *tot = run;
  }
}
__global__ __launch_bounds__(1024) void k_scan3(int* __restrict__ off, int* __restrict__ cur,
                                                const int* __restrict__ bsums, int n){
  int i = blockIdx.x*1024 + threadIdx.x;
  if (i<n){ int v = off[i] + bsums[blockIdx.x]; off[i]=v; cur[i]=v; }
}
__global__ void k_fill(const int* __restrict__ dst, const int* __restrict__ src,
                       int* __restrict__ cur, int* __restrict__ perm, int* __restrict__ srcP){
  int e = blockIdx.x*256 + threadIdx.x;
  int pos = atomicAdd(&cur[dst[e]], 1);
  perm[e] = pos;
  srcP[pos] = src[e];
}
__global__ void k_prev(const int* __restrict__ rev, const int* __restrict__ perm, int* __restrict__ prevP){
  int e = blockIdx.x*256 + threadIdx.x;
  prevP[perm[e]] = perm[rev[e]];
}

// ---------------- final: relu(e2n)@Wo+bo -> relu -> graph segsum ----------------
__global__ __launch_bounds__(256) void k_final(const u16* __restrict__ e2nb, const float* __restrict__ Wo,
                                               const float* __restrict__ bo, const int* __restrict__ gid,
                                               float* __restrict__ yacc){
  __shared__ float w[D*D];
  for (int i=threadIdx.x;i<D*D;i+=256) w[i]=Wo[i];
  __syncthreads();
  const int d = threadIdx.x&63, sub = threadIdx.x>>6;
  const int n0 = blockIdx.x*32 + sub*8;
  const float bod = bo[d];
  float acc=0.f; int curg=-1;
  for (int i=0;i<8;i++){
    int n=n0+i;
    if (n>=NN) break;
    int g = gid[n];
    if (g!=curg){ if (curg>=0) atomicAdd(&yacc[curg*D+d], acc); curg=g; acc=0.f; }
    float v=bod;
    const u16* er = e2nb + (size_t)n*D;
    #pragma unroll 8
    for (int k=0;k<D;k++){ float h=b2f(er[k]); h = h>0.f?h:0.f; v += h*w[k*D+d]; }
    acc += (v>0.f ? v : 0.f);
  }
  if (curg>=0) atomicAdd(&yacc[curg*D+d], acc);
}
__global__ void k_out(const float* __restrict__ yacc, float* __restrict__ outp){
  int i = blockIdx.x*256 + threadIdx.x;
  if (i<NG*D){ float v=yacc[i]; outp[i]= v>0.f?v:0.f; }
}

// ---------------- workspace layout ----------------
static constexpr size_t SZ_E   = (size_t)NE*D*2;          // 102.4 MB bf16 edge array
static constexpr size_t SZ_NB  = (size_t)NN*D*2;          // 6.4 MB bf16 node array
static constexpr size_t OFF_IMP  = 0;
static constexpr size_t OFF_CPA  = SZ_E;
static constexpr size_t OFF_CPB  = 2*SZ_E;
static constexpr size_t OFF_NAB  = 3*SZ_E;                // naW / e2n (bf16)
static constexpr size_t OFF_INL  = OFF_NAB + SZ_NB;       // fp32 node linear
static constexpr size_t OFF_COFF = OFF_INL + (size_t)NN*D*4;
static constexpr size_t OFF_CCUR = OFF_COFF + 200064;
static constexpr size_t OFF_PERM = OFF_CCUR + 200064;
static constexpr size_t OFF_SRCP = OFF_PERM + (size_t)NE*4;
static constexpr size_t OFF_PRVP = OFF_SRCP + (size_t)NE*4;
static constexpr size_t OFF_BS   = OFF_PRVP + (size_t)NE*4;
static constexpr size_t OFF_YACC = OFF_BS + 256;

extern "C" void kernel_launch(void* const* d_in, const int* in_sizes, int n_in,
                              void* d_out, int out_size, void* d_ws, size_t ws_size,
                              hipStream_t stream) {
  const float* node_feat = (const float*)d_in[0];
  const float* edge_feat = (const float*)d_in[1];
  const int*   src       = (const int*)d_in[2];
  const int*   dst       = (const int*)d_in[3];
  const int*   rev       = (const int*)d_in[4];
  const int*   gid       = (const int*)d_in[5];
  const float* Wn = (const float*)d_in[7];
  const float* bn = (const float*)d_in[8];
  const float* We = (const float*)d_in[9];
  const float* be = (const float*)d_in[10];
  const float* Wc = (const float*)d_in[11];
  const float* bc = (const float*)d_in[12];
  const float* Wo = (const float*)d_in[13];
  const float* bo = (const float*)d_in[14];

  char* ws = (char*)d_ws;
  u16*   imP     = (u16*)(ws + OFF_IMP);
  u16*   curPA   = (u16*)(ws + OFF_CPA);
  u16*   curPB   = (u16*)(ws + OFF_CPB);
  u16*   naWb    = (u16*)(ws + OFF_NAB);
  float* inl     = (float*)(ws + OFF_INL);
  int*   csr_off = (int*)(ws + OFF_COFF);
  int*   csr_cur = (int*)(ws + OFF_CCUR);
  int*   perm    = (int*)(ws + OFF_PERM);
  int*   srcP    = (int*)(ws + OFF_SRCP);
  int*   prevP   = (int*)(ws + OFF_PRVP);
  int*   bsums   = (int*)(ws + OFF_BS);
  float* yacc    = (float*)(ws + OFF_YACC);

  hipMemsetAsync(csr_cur, 0, NN*sizeof(int), stream);
  hipMemsetAsync(yacc, 0, NG*D*sizeof(float), stream);

  // CSR build: offsets + perm + permuted index arrays
  k_hist <<<NE/256, 256, 0, stream>>>(dst, csr_cur);
  k_scan1<<<49, 1024, 0, stream>>>(csr_cur, csr_off, bsums, NN);
  k_scan2<<<1, 64, 0, stream>>>(bsums, 49, csr_off + NN);
  k_scan3<<<49, 1024, 0, stream>>>(csr_off, csr_cur, bsums, NN);
  k_fill <<<NE/256, 256, 0, stream>>>(dst, src, csr_cur, perm, srcP);
  k_prev <<<NE/256, 256, 0, stream>>>(rev, perm, prevP);

  // front end
  k_inl<<<NN/4, 256, 0, stream>>>(node_feat, Wn, bn, inl);
  k_im <<<NE/(64*GPW), 256, 0, stream>>>(edge_feat, We, be, inl, src, perm, imP);

  // curW_0 = relu(im) @ Wc (slot order)
  k_iter<0><<<NE/(64*GPW), 256, 0, stream>>>(imP, curPA, naWb, Wc, bc, srcP, prevP, curPA);
  k_seg<<<NN/4, 256, 0, stream>>>(curPA, csr_off, naWb);
  k_iter<1><<<NE/(64*GPW), 256, 0, stream>>>(imP, curPA, naWb, Wc, bc, srcP, prevP, curPB);
  k_seg<<<NN/4, 256, 0, stream>>>(curPB, csr_off, naWb);
  k_iter<1><<<NE/(64*GPW), 256, 0, stream>>>(imP, curPB, naWb, Wc, bc, srcP, prevP, curPA);
  k_seg<<<NN/4, 256, 0, stream>>>(curPA, csr_off, naWb);
  k_iter<2><<<NE/(64*GPW), 256, 0, stream>>>(imP, curPA, naWb, Wc, bc, srcP, prevP, curPB);

  // e2n pool (reuse naWb) + head
  k_seg<<<NN/4, 256, 0, stream>>>(curPB, csr_off, naWb);
  k_final<<<(NN+31)/32, 256, 0, stream>>>(naWb, Wo, bo, gid, yacc);
  k_out<<<(NG*D)/256, 256, 0, stream>>>(yacc, (float*)d_out);
}

// Round 4
// 736.237 us; speedup vs baseline: 1.1401x; 1.1401x over previous
//
#include <hip/hip_runtime.h>

// EmbedLoopyBP on gfx950 — round 4.
// R2's LDS-staged pipelines + R3's CSR(dst)-slot ordering. All k_iter reads
// (imP) and writes (outP) are sequential streams; the only gather is
// cinP[prevP[slot]] (bijective 128B rows) + small L2-resident naWb/inlb.
// Bank-conflict pads: xs/wts stride 66 u16, os stride 68 (all <=2-way).

#define NN 50000
#define NE 800000
#define NG 128
#define D 64
#define LDE 36
#define LDW 66
#define LDO 68

typedef unsigned short u16;
typedef unsigned int u32;
typedef __bf16 bf16x8 __attribute__((ext_vector_type(8)));
typedef float f32x4 __attribute__((ext_vector_type(4)));

__device__ __forceinline__ float b2f(u16 u){ u32 x=((u32)u)<<16; float f; __builtin_memcpy(&f,&x,4); return f; }
__device__ __forceinline__ u16 f2b(float f){ u32 x; __builtin_memcpy(&x,&f,4); x += 0x7fffu + ((x>>16)&1u); return (u16)(x>>16); }
__device__ __forceinline__ u32 pack2(float a, float b){ return (u32)f2b(a) | ((u32)f2b(b)<<16); }
__device__ __forceinline__ void unpack8(uint4 v, float* o){
  o[0]=b2f((u16)(v.x&0xffffu)); o[1]=b2f((u16)(v.x>>16));
  o[2]=b2f((u16)(v.y&0xffffu)); o[3]=b2f((u16)(v.y>>16));
  o[4]=b2f((u16)(v.z&0xffffu)); o[5]=b2f((u16)(v.z>>16));
  o[6]=b2f((u16)(v.w&0xffffu)); o[7]=b2f((u16)(v.w>>16));
}

// ---------------- node linear: inlb = bf16(node_feat @ Wn + bn) ----------------
__global__ __launch_bounds__(256) void k_inl(const float* __restrict__ nf, const float* __restrict__ Wn,
                                             const float* __restrict__ bn, u16* __restrict__ inlb){
  __shared__ float w[D*D];
  for (int i=threadIdx.x;i<D*D;i+=256) w[i]=Wn[i];
  __syncthreads();
  const int d = threadIdx.x&63;
  const int n = blockIdx.x*4 + (threadIdx.x>>6);
  if (n>=NN) return;
  float v = bn[d];
  const float* row = nf + (size_t)n*D;
  #pragma unroll 8
  for (int k=0;k<D;k++) v += row[k]*w[k*D+d];
  inlb[(size_t)n*D+d] = f2b(v);
}

// ---------------- imP[perm[e]] = edge_feat@We + be + inl[src[e]]  (bf16) ----------------
__global__ __launch_bounds__(256) void k_im(const float* __restrict__ ef, const float* __restrict__ We,
                                            const float* __restrict__ be, const u16* __restrict__ inlb,
                                            const int* __restrict__ src, const int* __restrict__ perm,
                                            u16* __restrict__ imP){
  __shared__ __align__(16) u16 efs[64*LDE];
  __shared__ __align__(16) u16 wts[64*LDE];
  __shared__ float os[64*LDO];
  const int t = threadIdx.x;
  const int ebase = blockIdx.x*64;
  { // stage We^T bf16 : wts[n][k], k<32
    int n=t&63, k0=(t>>6)*8;
    #pragma unroll
    for (int j=0;j<8;j++) wts[n*LDE + k0 + j] = f2b(We[(k0+j)*D + n]);
  }
  { // stage edge_feat bf16 (coalesced float4 reads)
    int e=t>>2, k0=(t&3)*8;
    const float* p = ef + (size_t)(ebase+e)*32 + k0;
    float4 v0=*(const float4*)p, v1=*(const float4*)(p+4);
    uint4 pk = make_uint4(pack2(v0.x,v0.y),pack2(v0.z,v0.w),pack2(v1.x,v1.y),pack2(v1.z,v1.w));
    *(uint4*)&efs[e*LDE + k0] = pk;
  }
  __syncthreads();
  { // MFMA 16x16x32 (K=32, one step)
    int w=t>>6, lane=t&63, q=lane>>4, mr=lane&15;
    int rowb=w*16;
    bf16x8 A = *(const bf16x8*)&efs[(rowb+mr)*LDE + q*8];
    #pragma unroll
    for (int nt=0;nt<4;nt++){
      bf16x8 B = *(const bf16x8*)&wts[(nt*16+mr)*LDE + q*8];
      f32x4 acc = {0.f,0.f,0.f,0.f};
      acc = __builtin_amdgcn_mfma_f32_16x16x32_bf16(A,B,acc,0,0,0);
      #pragma unroll
      for (int r=0;r<4;r++) os[(rowb+q*4+r)*LDO + nt*16+mr] = acc[r];
    }
  }
  __syncthreads();
  { // epilogue: + be + inlb[src[e]] -> bf16, full-row scatter to imP[perm[e]]
    int e=t>>2, d0=(t&3)*16;
    const size_t eg = (size_t)(ebase+e);
    const int s = src[eg], ps = perm[eg];
    const u16* ip = inlb + (size_t)s*D + d0;
    uint4 iv0 = *(const uint4*)ip, iv1 = *(const uint4*)(ip+8);
    float il[16]; unpack8(iv0,il); unpack8(iv1,il+8);
    float x[16];
    #pragma unroll
    for (int j=0;j<16;j++) x[j] = os[e*LDO + d0 + j] + be[d0+j] + il[j];
    uint4 p0 = make_uint4(pack2(x[0],x[1]),pack2(x[2],x[3]),pack2(x[4],x[5]),pack2(x[6],x[7]));
    uint4 p1 = make_uint4(pack2(x[8],x[9]),pack2(x[10],x[11]),pack2(x[12],x[13]),pack2(x[14],x[15]));
    u16* op = imP + (size_t)ps*D + d0;
    *(uint4*)op = p0; *(uint4*)(op+8) = p1;
  }
}

// ---------------- iteration kernel (slot order, LDS-staged MFMA) ----------------
// MODE 0: x=relu(imP[slot]);                             outP[slot]=(x@Wc) bf16
// MODE 1: x=relu(naWb[srcP]-cinP[prevP]+bc+imP[slot]);   outP[slot]=(x@Wc) bf16
template<int MODE>
__global__ __launch_bounds__(256) void k_iter(const u16* __restrict__ imP, const u16* __restrict__ cinP,
      const u16* __restrict__ naWb, const float* __restrict__ Wc, const float* __restrict__ bc,
      const int* __restrict__ srcP, const int* __restrict__ prevP, u16* __restrict__ outP){
  __shared__ __align__(16) u16 xs[64*LDW];
  __shared__ __align__(16) u16 wts[64*LDW];
  __shared__ __align__(16) u16 os[4][16*LDO];
  const int t = threadIdx.x;
  const size_t sbase = (size_t)blockIdx.x*64;
  { // stage Wc^T bf16 : wts[n][k]
    int n=t&63, k0=(t>>6)*16;
    #pragma unroll
    for (int j=0;j<16;j++) wts[n*LDW + k0 + j] = f2b(Wc[(k0+j)*D + n]);
  }
  { // phase 1: elementwise, 4 threads per slot row (all streams except cinP row gather)
    const int e = t>>2, d0 = (t&3)*16;
    const size_t slot = sbase + e;
    const u16* ip = imP + slot*D + d0;
    uint4 r0 = *(const uint4*)ip;
    uint4 r1 = *(const uint4*)(ip+8);
    float x[16];
    unpack8(r0, x); unpack8(r1, x+8);
    if (MODE == 1){
      const int pv = prevP[slot], sp = srcP[slot];
      const u16* cp = cinP + (size_t)pv*D + d0;
      uint4 c0 = *(const uint4*)cp, c1 = *(const uint4*)(cp+8);
      const u16* np_ = naWb + (size_t)sp*D + d0;
      uint4 n0 = *(const uint4*)np_, n1 = *(const uint4*)(np_+8);
      float cv[16], nv[16];
      unpack8(c0,cv); unpack8(c1,cv+8);
      unpack8(n0,nv); unpack8(n1,nv+8);
      #pragma unroll
      for (int j=0;j<16;j++) x[j] += nv[j] - cv[j] + bc[d0+j];
    }
    #pragma unroll
    for (int j=0;j<16;j++) x[j] = x[j]>0.f ? x[j] : 0.f;
    uint4 p0 = make_uint4(pack2(x[0],x[1]),pack2(x[2],x[3]),pack2(x[4],x[5]),pack2(x[6],x[7]));
    uint4 p1 = make_uint4(pack2(x[8],x[9]),pack2(x[10],x[11]),pack2(x[12],x[13]),pack2(x[14],x[15]));
    u16* q = &xs[e*LDW + d0];
    *(uint4*)q = p0; *(uint4*)(q+8) = p1;
  }
  __syncthreads();
  { // phase 2: x @ Wc via MFMA, K=64 = 2 ksteps; sequential 16B stores
    const int w=t>>6, lane=t&63, q=lane>>4, mr=lane&15;
    const int rowb = w*16;
    bf16x8 A0 = *(const bf16x8*)&xs[(rowb+mr)*LDW + q*8];
    bf16x8 A1 = *(const bf16x8*)&xs[(rowb+mr)*LDW + 32 + q*8];
    #pragma unroll
    for (int nt=0;nt<4;nt++){
      bf16x8 B0 = *(const bf16x8*)&wts[(nt*16+mr)*LDW + q*8];
      bf16x8 B1 = *(const bf16x8*)&wts[(nt*16+mr)*LDW + 32 + q*8];
      f32x4 acc = {0.f,0.f,0.f,0.f};
      acc = __builtin_amdgcn_mfma_f32_16x16x32_bf16(A0,B0,acc,0,0,0);
      acc = __builtin_amdgcn_mfma_f32_16x16x32_bf16(A1,B1,acc,0,0,0);
      #pragma unroll
      for (int r=0;r<4;r++) os[w][(q*4+r)*LDO + nt*16 + mr] = f2b(acc[r]);
    }
    const int lr = lane>>2, cc = lane&3;   // wave-local os, no barrier needed
    u16* gp = outP + (sbase + rowb + lr)*D + cc*16;
    *(uint4*)gp     = *(const uint4*)&os[w][lr*LDO + cc*16];
    *(uint4*)(gp+8) = *(const uint4*)&os[w][lr*LDO + cc*16 + 8];
  }
}

// ---------------- final BP step (no matmul): outP[slot] = x ----------------
__global__ __launch_bounds__(256) void k_last(const u16* __restrict__ imP, const u16* __restrict__ cinP,
      const u16* __restrict__ naWb, const float* __restrict__ bc,
      const int* __restrict__ srcP, const int* __restrict__ prevP, u16* __restrict__ outP){
  const int t = threadIdx.x;
  const int e = t>>2, d0 = (t&3)*16;
  const size_t slot = (size_t)blockIdx.x*64 + e;
  const u16* ip = imP + slot*D + d0;
  uint4 r0 = *(const uint4*)ip, r1 = *(const uint4*)(ip+8);
  float x[16];
  unpack8(r0, x); unpack8(r1, x+8);
  const int pv = prevP[slot], sp = srcP[slot];
  const u16* cp = cinP + (size_t)pv*D + d0;
  uint4 c0 = *(const uint4*)cp, c1 = *(const uint4*)(cp+8);
  const u16* np_ = naWb + (size_t)sp*D + d0;
  uint4 n0 = *(const uint4*)np_, n1 = *(const uint4*)(np_+8);
  float cv[16], nv[16];
  unpack8(c0,cv); unpack8(c1,cv+8);
  unpack8(n0,nv); unpack8(n1,nv+8);
  #pragma unroll
  for (int j=0;j<16;j++){ x[j] += nv[j] - cv[j] + bc[d0+j]; x[j] = x[j]>0.f ? x[j] : 0.f; }
  uint4 p0 = make_uint4(pack2(x[0],x[1]),pack2(x[2],x[3]),pack2(x[4],x[5]),pack2(x[6],x[7]));
  uint4 p1 = make_uint4(pack2(x[8],x[9]),pack2(x[10],x[11]),pack2(x[12],x[13]),pack2(x[14],x[15]));
  u16* op = outP + slot*D + d0;
  *(uint4*)op = p0; *(uint4*)(op+8) = p1;
}

// ---------------- streaming segment sum -> bf16 node rows ----------------
__global__ __launch_bounds__(256) void k_seg(const u16* __restrict__ curP, const int* __restrict__ off,
                                             u16* __restrict__ outb){
  const int n = blockIdx.x*4 + (threadIdx.x>>6);
  const int lane = threadIdx.x&63, rg = lane>>3, c8 = lane&7;
  if (n>=NN) return;
  const int p0=off[n], p1=off[n+1];
  float s[8] = {0.f,0.f,0.f,0.f,0.f,0.f,0.f,0.f};
  for (int p = p0+rg; p < p1; p += 8){
    uint4 v = *(const uint4*)(curP + (size_t)p*D + c8*8);
    float tv[8]; unpack8(v,tv);
    #pragma unroll
    for (int j=0;j<8;j++) s[j]+=tv[j];
  }
  #pragma unroll
  for (int j=0;j<8;j++) s[j] += __shfl_xor(s[j], 8, 64);
  #pragma unroll
  for (int j=0;j<8;j++) s[j] += __shfl_xor(s[j], 16, 64);
  #pragma unroll
  for (int j=0;j<8;j++) s[j] += __shfl_xor(s[j], 32, 64);
  if (rg==0){
    uint4 o = make_uint4(pack2(s[0],s[1]),pack2(s[2],s[3]),pack2(s[4],s[5]),pack2(s[6],s[7]));
    *(uint4*)(outb + (size_t)n*D + c8*8) = o;
  }
}

// ---------------- CSR build ----------------
__global__ void k_hist(const int* __restrict__ dst, int* __restrict__ cnt){
  int e = blockIdx.x*256 + threadIdx.x;
  atomicAdd(&cnt[dst[e]], 1);
}
__global__ __launch_bounds__(1024) void k_scan1(const int* __restrict__ cnt, int* __restrict__ outv,
                                                int* __restrict__ bsums, int n){
  __shared__ int sh[1024];
  int i = blockIdx.x*1024 + threadIdx.x;
  int v = (i<n)? cnt[i] : 0;
  sh[threadIdx.x]=v;
  __syncthreads();
  for (int off=1; off<1024; off<<=1){
    int tv = (threadIdx.x>=(unsigned)off)? sh[threadIdx.x-off] : 0;
    __syncthreads();
    sh[threadIdx.x] += tv;
    __syncthreads();
  }
  if (i<n) outv[i] = sh[threadIdx.x] - v;
  if (threadIdx.x==1023) bsums[blockIdx.x] = sh[1023];
}
__global__ void k_scan2(int* bsums, int nb, int* tot){
  if (threadIdx.x==0 && blockIdx.x==0){
    int run=0;
    for (int b=0;b<nb;b++){ int v=bsums[b]; bsums[b]=run; run+=v; }
    *tot = run;
  }
}
__global__ __launch_bounds__(1024) void k_scan3(int* __restrict__ off, int* __restrict__ cur,
                                                const int* __restrict__ bsums, int n){
  int i = blockIdx.x*1024 + threadIdx.x;
  if (i<n){ int v = off[i] + bsums[blockIdx.x]; off[i]=v; cur[i]=v; }
}
__global__ void k_fill(const int* __restrict__ dst, const int* __restrict__ src,
                       int* __restrict__ cur, int* __restrict__ perm, int* __restrict__ srcP){
  int e = blockIdx.x*256 + threadIdx.x;
  int pos = atomicAdd(&cur[dst[e]], 1);
  perm[e] = pos;
  srcP[pos] = src[e];
}
__global__ void k_prev(const int* __restrict__ rev, const int* __restrict__ perm, int* __restrict__ prevP){
  int e = blockIdx.x*256 + threadIdx.x;
  prevP[perm[e]] = perm[rev[e]];
}

// ---------------- final: relu(e2n)@Wo+bo -> relu -> graph segsum ----------------
__global__ __launch_bounds__(256) void k_final(const u16* __restrict__ e2nb, const float* __restrict__ Wo,
                                               const float* __restrict__ bo, const int* __restrict__ gid,
                                               float* __restrict__ yacc){
  __shared__ float w[D*D];
  for (int i=threadIdx.x;i<D*D;i+=256) w[i]=Wo[i];
  __syncthreads();
  const int d = threadIdx.x&63, sub = threadIdx.x>>6;
  const int n0 = blockIdx.x*32 + sub*8;
  const float bod = bo[d];
  float acc=0.f; int curg=-1;
  for (int i=0;i<8;i++){
    int n=n0+i;
    if (n>=NN) break;
    int g = gid[n];
    if (g!=curg){ if (curg>=0) atomicAdd(&yacc[curg*D+d], acc); curg=g; acc=0.f; }
    float v=bod;
    const u16* er = e2nb + (size_t)n*D;
    #pragma unroll 8
    for (int k=0;k<D;k++){ float h=b2f(er[k]); h = h>0.f?h:0.f; v += h*w[k*D+d]; }
    acc += (v>0.f ? v : 0.f);
  }
  if (curg>=0) atomicAdd(&yacc[curg*D+d], acc);
}
__global__ void k_out(const float* __restrict__ yacc, float* __restrict__ outp){
  int i = blockIdx.x*256 + threadIdx.x;
  if (i<NG*D){ float v=yacc[i]; outp[i]= v>0.f?v:0.f; }
}

// ---------------- workspace layout ----------------
static constexpr size_t SZ_E   = (size_t)NE*D*2;          // 102.4 MB bf16 edge array
static constexpr size_t SZ_NB  = (size_t)NN*D*2;          // 6.4 MB bf16 node array
static constexpr size_t OFF_IMP  = 0;
static constexpr size_t OFF_CPA  = SZ_E;
static constexpr size_t OFF_CPB  = 2*SZ_E;
static constexpr size_t OFF_NAB  = 3*SZ_E;                // naW / e2n (bf16)
static constexpr size_t OFF_INL  = OFF_NAB + SZ_NB;       // bf16 node linear
static constexpr size_t OFF_COFF = OFF_INL + SZ_NB;
static constexpr size_t OFF_CCUR = OFF_COFF + 200064;
static constexpr size_t OFF_PERM = OFF_CCUR + 200064;
static constexpr size_t OFF_SRCP = OFF_PERM + (size_t)NE*4;
static constexpr size_t OFF_PRVP = OFF_SRCP + (size_t)NE*4;
static constexpr size_t OFF_BS   = OFF_PRVP + (size_t)NE*4;
static constexpr size_t OFF_YACC = OFF_BS + 256;

extern "C" void kernel_launch(void* const* d_in, const int* in_sizes, int n_in,
                              void* d_out, int out_size, void* d_ws, size_t ws_size,
                              hipStream_t stream) {
  const float* node_feat = (const float*)d_in[0];
  const float* edge_feat = (const float*)d_in[1];
  const int*   src       = (const int*)d_in[2];
  const int*   dst       = (const int*)d_in[3];
  const int*   rev       = (const int*)d_in[4];
  const int*   gid       = (const int*)d_in[5];
  const float* Wn = (const float*)d_in[7];
  const float* bn = (const float*)d_in[8];
  const float* We = (const float*)d_in[9];
  const float* be = (const float*)d_in[10];
  const float* Wc = (const float*)d_in[11];
  const float* bc = (const float*)d_in[12];
  const float* Wo = (const float*)d_in[13];
  const float* bo = (const float*)d_in[14];

  char* ws = (char*)d_ws;
  u16*   imP     = (u16*)(ws + OFF_IMP);
  u16*   curPA   = (u16*)(ws + OFF_CPA);
  u16*   curPB   = (u16*)(ws + OFF_CPB);
  u16*   naWb    = (u16*)(ws + OFF_NAB);
  u16*   inlb    = (u16*)(ws + OFF_INL);
  int*   csr_off = (int*)(ws + OFF_COFF);
  int*   csr_cur = (int*)(ws + OFF_CCUR);
  int*   perm    = (int*)(ws + OFF_PERM);
  int*   srcP    = (int*)(ws + OFF_SRCP);
  int*   prevP   = (int*)(ws + OFF_PRVP);
  int*   bsums   = (int*)(ws + OFF_BS);
  float* yacc    = (float*)(ws + OFF_YACC);

  hipMemsetAsync(csr_cur, 0, NN*sizeof(int), stream);
  hipMemsetAsync(yacc, 0, NG*D*sizeof(float), stream);

  // CSR build: offsets + perm + permuted index arrays
  k_hist <<<NE/256, 256, 0, stream>>>(dst, csr_cur);
  k_scan1<<<49, 1024, 0, stream>>>(csr_cur, csr_off, bsums, NN);
  k_scan2<<<1, 64, 0, stream>>>(bsums, 49, csr_off + NN);
  k_scan3<<<49, 1024, 0, stream>>>(csr_off, csr_cur, bsums, NN);
  k_fill <<<NE/256, 256, 0, stream>>>(dst, src, csr_cur, perm, srcP);
  k_prev <<<NE/256, 256, 0, stream>>>(rev, perm, prevP);

  // front end
  k_inl<<<NN/4, 256, 0, stream>>>(node_feat, Wn, bn, inlb);
  k_im <<<NE/64, 256, 0, stream>>>(edge_feat, We, be, inlb, src, perm, imP);

  // loopy BP
  k_iter<0><<<NE/64, 256, 0, stream>>>(imP, curPA, naWb, Wc, bc, srcP, prevP, curPA);
  k_seg<<<NN/4, 256, 0, stream>>>(curPA, csr_off, naWb);
  k_iter<1><<<NE/64, 256, 0, stream>>>(imP, curPA, naWb, Wc, bc, srcP, prevP, curPB);
  k_seg<<<NN/4, 256, 0, stream>>>(curPB, csr_off, naWb);
  k_iter<1><<<NE/64, 256, 0, stream>>>(imP, curPB, naWb, Wc, bc, srcP, prevP, curPA);
  k_seg<<<NN/4, 256, 0, stream>>>(curPA, csr_off, naWb);
  k_last<<<NE/64, 256, 0, stream>>>(imP, curPA, naWb, bc, srcP, prevP, curPB);

  // e2n pool (reuse naWb) + head
  k_seg<<<NN/4, 256, 0, stream>>>(curPB, csr_off, naWb);
  k_final<<<(NN+31)/32, 256, 0, stream>>>(naWb, Wo, bo, gid, yacc);
  k_out<<<(NG*D)/256, 256, 0, stream>>>(yacc, (float*)d_out);
}

// Round 5
// 715.710 us; speedup vs baseline: 1.1728x; 1.0287x over previous
//
#include <hip/hip_runtime.h>

// EmbedLoopyBP on gfx950 — round 5.
// R4 structure + fused segment-sum: CSR-slot order means each block's 64 rows
// are contiguous slots, so the per-node sum is a block-local segmented
// reduction (node ids staged in LDS) flushed via 64-lane row atomicAdds into
// pre-zeroed fp32 naW (L3-resident). Eliminates all 5 k_seg passes and
// k_last's 102MB curP write.

#define NN 50000
#define NE 800000
#define NG 128
#define D 64
#define LDE 36
#define LDW 66
#define LDO 72

typedef unsigned short u16;
typedef unsigned int u32;
typedef __bf16 bf16x8 __attribute__((ext_vector_type(8)));
typedef float f32x4 __attribute__((ext_vector_type(4)));

__device__ __forceinline__ float b2f(u16 u){ u32 x=((u32)u)<<16; float f; __builtin_memcpy(&f,&x,4); return f; }
__device__ __forceinline__ u16 f2b(float f){ u32 x; __builtin_memcpy(&x,&f,4); x += 0x7fffu + ((x>>16)&1u); return (u16)(x>>16); }
__device__ __forceinline__ u32 pack2(float a, float b){ return (u32)f2b(a) | ((u32)f2b(b)<<16); }
__device__ __forceinline__ void unpack8(uint4 v, float* o){
  o[0]=b2f((u16)(v.x&0xffffu)); o[1]=b2f((u16)(v.x>>16));
  o[2]=b2f((u16)(v.y&0xffffu)); o[3]=b2f((u16)(v.y>>16));
  o[4]=b2f((u16)(v.z&0xffffu)); o[5]=b2f((u16)(v.z>>16));
  o[6]=b2f((u16)(v.w&0xffffu)); o[7]=b2f((u16)(v.w>>16));
}

// ---------------- node linear: inlb = bf16(node_feat @ Wn + bn) ----------------
__global__ __launch_bounds__(256) void k_inl(const float* __restrict__ nf, const float* __restrict__ Wn,
                                             const float* __restrict__ bn, u16* __restrict__ inlb){
  __shared__ float w[D*D];
  for (int i=threadIdx.x;i<D*D;i+=256) w[i]=Wn[i];
  __syncthreads();
  const int d = threadIdx.x&63;
  const int n = blockIdx.x*4 + (threadIdx.x>>6);
  if (n>=NN) return;
  float v = bn[d];
  const float* row = nf + (size_t)n*D;
  #pragma unroll 8
  for (int k=0;k<D;k++) v += row[k]*w[k*D+d];
  inlb[(size_t)n*D+d] = f2b(v);
}

// ---------------- imP[perm[e]] = edge_feat@We + be + inl[src[e]]  (bf16) ----------------
__global__ __launch_bounds__(256) void k_im(const float* __restrict__ ef, const float* __restrict__ We,
                                            const float* __restrict__ be, const u16* __restrict__ inlb,
                                            const int* __restrict__ src, const int* __restrict__ perm,
                                            u16* __restrict__ imP){
  __shared__ __align__(16) u16 efs[64*LDE];
  __shared__ __align__(16) u16 wts[64*LDE];
  __shared__ float os[64*68];
  const int t = threadIdx.x;
  const int ebase = blockIdx.x*64;
  { // stage We^T bf16 : wts[n][k], k<32
    int n=t&63, k0=(t>>6)*8;
    #pragma unroll
    for (int j=0;j<8;j++) wts[n*LDE + k0 + j] = f2b(We[(k0+j)*D + n]);
  }
  { // stage edge_feat bf16 (coalesced float4 reads)
    int e=t>>2, k0=(t&3)*8;
    const float* p = ef + (size_t)(ebase+e)*32 + k0;
    float4 v0=*(const float4*)p, v1=*(const float4*)(p+4);
    uint4 pk = make_uint4(pack2(v0.x,v0.y),pack2(v0.z,v0.w),pack2(v1.x,v1.y),pack2(v1.z,v1.w));
    *(uint4*)&efs[e*LDE + k0] = pk;
  }
  __syncthreads();
  { // MFMA 16x16x32 (K=32, one step)
    int w=t>>6, lane=t&63, q=lane>>4, mr=lane&15;
    int rowb=w*16;
    bf16x8 A = *(const bf16x8*)&efs[(rowb+mr)*LDE + q*8];
    #pragma unroll
    for (int nt=0;nt<4;nt++){
      bf16x8 B = *(const bf16x8*)&wts[(nt*16+mr)*LDE + q*8];
      f32x4 acc = {0.f,0.f,0.f,0.f};
      acc = __builtin_amdgcn_mfma_f32_16x16x32_bf16(A,B,acc,0,0,0);
      #pragma unroll
      for (int r=0;r<4;r++) os[(rowb+q*4+r)*68 + nt*16+mr] = acc[r];
    }
  }
  __syncthreads();
  { // epilogue: + be + inlb[src[e]] -> bf16, full-row scatter to imP[perm[e]]
    int e=t>>2, d0=(t&3)*16;
    const size_t eg = (size_t)(ebase+e);
    const int s = src[eg], ps = perm[eg];
    const u16* ip = inlb + (size_t)s*D + d0;
    uint4 iv0 = *(const uint4*)ip, iv1 = *(const uint4*)(ip+8);
    float il[16]; unpack8(iv0,il); unpack8(iv1,il+8);
    float x[16];
    #pragma unroll
    for (int j=0;j<16;j++) x[j] = os[e*68 + d0 + j] + be[d0+j] + il[j];
    uint4 p0 = make_uint4(pack2(x[0],x[1]),pack2(x[2],x[3]),pack2(x[4],x[5]),pack2(x[6],x[7]));
    uint4 p1 = make_uint4(pack2(x[8],x[9]),pack2(x[10],x[11]),pack2(x[12],x[13]),pack2(x[14],x[15]));
    u16* op = imP + (size_t)ps*D + d0;
    *(uint4*)op = p0; *(uint4*)(op+8) = p1;
  }
}

// ---------------- iteration kernel (slot order, fused node reduction) ----------------
// MODE 0: x=relu(imP[slot]);                            outP[slot]=(x@Wc); naW_out += per-node
// MODE 1: x=relu(naW_in[srcP]-cinP[prevP]+bc+imP[slot]); same outputs
template<int MODE>
__global__ __launch_bounds__(256) void k_iter(const u16* __restrict__ imP, const u16* __restrict__ cinP,
      const float* __restrict__ naW_in, const float* __restrict__ Wc, const float* __restrict__ bc,
      const int* __restrict__ srcP, const int* __restrict__ prevP, const int* __restrict__ nodeP,
      u16* __restrict__ outP, float* __restrict__ naW_out){
  __shared__ __align__(16) u16 xs[64*LDW];
  __shared__ __align__(16) u16 wts[64*LDW];
  __shared__ __align__(16) u16 os[64*LDO];
  __shared__ int nid[64];
  const int t = threadIdx.x;
  const size_t sbase = (size_t)blockIdx.x*64;
  { // stage Wc^T bf16 : wts[n][k]
    int n=t&63, k0=(t>>6)*16;
    #pragma unroll
    for (int j=0;j<16;j++) wts[n*LDW + k0 + j] = f2b(Wc[(k0+j)*D + n]);
  }
  if (t < 64) nid[t] = nodeP[sbase + t];
  { // phase 1: elementwise, 4 threads per slot row
    const int e = t>>2, d0 = (t&3)*16;
    const size_t slot = sbase + e;
    const u16* ip = imP + slot*D + d0;
    uint4 r0 = *(const uint4*)ip;
    uint4 r1 = *(const uint4*)(ip+8);
    float x[16];
    unpack8(r0, x); unpack8(r1, x+8);
    if (MODE == 1){
      const int pv = prevP[slot], sp = srcP[slot];
      const u16* cp = cinP + (size_t)pv*D + d0;
      uint4 c0 = *(const uint4*)cp, c1 = *(const uint4*)(cp+8);
      const float* np_ = naW_in + (size_t)sp*D + d0;
      float4 a0=*(const float4*)np_,     a1=*(const float4*)(np_+4);
      float4 a2=*(const float4*)(np_+8), a3=*(const float4*)(np_+12);
      float nv[16] = {a0.x,a0.y,a0.z,a0.w, a1.x,a1.y,a1.z,a1.w,
                      a2.x,a2.y,a2.z,a2.w, a3.x,a3.y,a3.z,a3.w};
      float cv[16];
      unpack8(c0,cv); unpack8(c1,cv+8);
      #pragma unroll
      for (int j=0;j<16;j++) x[j] += nv[j] - cv[j] + bc[d0+j];
    }
    #pragma unroll
    for (int j=0;j<16;j++) x[j] = x[j]>0.f ? x[j] : 0.f;
    uint4 p0 = make_uint4(pack2(x[0],x[1]),pack2(x[2],x[3]),pack2(x[4],x[5]),pack2(x[6],x[7]));
    uint4 p1 = make_uint4(pack2(x[8],x[9]),pack2(x[10],x[11]),pack2(x[12],x[13]),pack2(x[14],x[15]));
    u16* q = &xs[e*LDW + d0];
    *(uint4*)q = p0; *(uint4*)(q+8) = p1;
  }
  __syncthreads();
  { // phase 2: x @ Wc via MFMA, K=64 = 2 ksteps; sequential 16B global stores
    const int w=t>>6, lane=t&63, q=lane>>4, mr=lane&15;
    const int rowb = w*16;
    bf16x8 A0 = *(const bf16x8*)&xs[(rowb+mr)*LDW + q*8];
    bf16x8 A1 = *(const bf16x8*)&xs[(rowb+mr)*LDW + 32 + q*8];
    #pragma unroll
    for (int nt=0;nt<4;nt++){
      bf16x8 B0 = *(const bf16x8*)&wts[(nt*16+mr)*LDW + q*8];
      bf16x8 B1 = *(const bf16x8*)&wts[(nt*16+mr)*LDW + 32 + q*8];
      f32x4 acc = {0.f,0.f,0.f,0.f};
      acc = __builtin_amdgcn_mfma_f32_16x16x32_bf16(A0,B0,acc,0,0,0);
      acc = __builtin_amdgcn_mfma_f32_16x16x32_bf16(A1,B1,acc,0,0,0);
      #pragma unroll
      for (int r=0;r<4;r++) os[(rowb+q*4+r)*LDO + nt*16 + mr] = f2b(acc[r]);
    }
    const int lr = lane>>2, cc = lane&3;   // wave-local rows: no barrier needed yet
    u16* gp = outP + (sbase + rowb + lr)*D + cc*16;
    *(uint4*)gp     = *(const uint4*)&os[(rowb+lr)*LDO + cc*16];
    *(uint4*)(gp+8) = *(const uint4*)&os[(rowb+lr)*LDO + cc*16 + 8];
  }
  __syncthreads();
  { // fused segment sum: group g = wave handles rows g*16..g*16+15, lane = column
    const int d = t&63, g = t>>6;
    float acc = 0.f;
    int curn = nid[g*16];
    #pragma unroll 4
    for (int r = g*16; r < g*16+16; ++r){
      int n = nid[r];                        // wave-uniform
      if (n != curn){
        atomicAdd(&naW_out[(size_t)curn*D + d], acc);
        curn = n; acc = 0.f;
      }
      acc += b2f(os[r*LDO + d]);
    }
    atomicAdd(&naW_out[(size_t)curn*D + d], acc);
  }
}

// ---------------- final BP step: x only (no matmul); e2n += per-node ----------------
__global__ __launch_bounds__(256) void k_last(const u16* __restrict__ imP, const u16* __restrict__ cinP,
      const float* __restrict__ naW_in, const float* __restrict__ bc,
      const int* __restrict__ srcP, const int* __restrict__ prevP, const int* __restrict__ nodeP,
      float* __restrict__ e2n){
  __shared__ __align__(16) u16 xs[64*LDW];
  __shared__ int nid[64];
  const int t = threadIdx.x;
  const size_t sbase = (size_t)blockIdx.x*64;
  if (t < 64) nid[t] = nodeP[sbase + t];
  {
    const int e = t>>2, d0 = (t&3)*16;
    const size_t slot = sbase + e;
    const u16* ip = imP + slot*D + d0;
    uint4 r0 = *(const uint4*)ip, r1 = *(const uint4*)(ip+8);
    float x[16];
    unpack8(r0, x); unpack8(r1, x+8);
    const int pv = prevP[slot], sp = srcP[slot];
    const u16* cp = cinP + (size_t)pv*D + d0;
    uint4 c0 = *(const uint4*)cp, c1 = *(const uint4*)(cp+8);
    const float* np_ = naW_in + (size_t)sp*D + d0;
    float4 a0=*(const float4*)np_,     a1=*(const float4*)(np_+4);
    float4 a2=*(const float4*)(np_+8), a3=*(const float4*)(np_+12);
    float nv[16] = {a0.x,a0.y,a0.z,a0.w, a1.x,a1.y,a1.z,a1.w,
                    a2.x,a2.y,a2.z,a2.w, a3.x,a3.y,a3.z,a3.w};
    float cv[16];
    unpack8(c0,cv); unpack8(c1,cv+8);
    #pragma unroll
    for (int j=0;j<16;j++){ x[j] += nv[j] - cv[j] + bc[d0+j]; x[j] = x[j]>0.f ? x[j] : 0.f; }
    uint4 p0 = make_uint4(pack2(x[0],x[1]),pack2(x[2],x[3]),pack2(x[4],x[5]),pack2(x[6],x[7]));
    uint4 p1 = make_uint4(pack2(x[8],x[9]),pack2(x[10],x[11]),pack2(x[12],x[13]),pack2(x[14],x[15]));
    u16* q = &xs[e*LDW + d0];
    *(uint4*)q = p0; *(uint4*)(q+8) = p1;
  }
  __syncthreads();
  {
    const int d = t&63, g = t>>6;
    float acc = 0.f;
    int curn = nid[g*16];
    #pragma unroll 4
    for (int r = g*16; r < g*16+16; ++r){
      int n = nid[r];
      if (n != curn){
        atomicAdd(&e2n[(size_t)curn*D + d], acc);
        curn = n; acc = 0.f;
      }
      acc += b2f(xs[r*LDW + d]);
    }
    atomicAdd(&e2n[(size_t)curn*D + d], acc);
  }
}

// ---------------- CSR build ----------------
__global__ void k_hist(const int* __restrict__ dst, int* __restrict__ cnt){
  int e = blockIdx.x*256 + threadIdx.x;
  atomicAdd(&cnt[dst[e]], 1);
}
__global__ __launch_bounds__(1024) void k_scan1(const int* __restrict__ cnt, int* __restrict__ outv,
                                                int* __restrict__ bsums, int n){
  __shared__ int sh[1024];
  int i = blockIdx.x*1024 + threadIdx.x;
  int v = (i<n)? cnt[i] : 0;
  sh[threadIdx.x]=v;
  __syncthreads();
  for (int off=1; off<1024; off<<=1){
    int tv = (threadIdx.x>=(unsigned)off)? sh[threadIdx.x-off] : 0;
    __syncthreads();
    sh[threadIdx.x] += tv;
    __syncthreads();
  }
  if (i<n) outv[i] = sh[threadIdx.x] - v;
  if (threadIdx.x==1023) bsums[blockIdx.x] = sh[1023];
}
__global__ void k_scan2(int* bsums, int nb, int* tot){
  if (threadIdx.x==0 && blockIdx.x==0){
    int run=0;
    for (int b=0;b<nb;b++){ int v=bsums[b]; bsums[b]=run; run+=v; }
    *tot = run;
  }
}
__global__ __launch_bounds__(1024) void k_scan3(int* __restrict__ off, int* __restrict__ cur,
                                                const int* __restrict__ bsums, int n){
  int i = blockIdx.x*1024 + threadIdx.x;
  if (i<n){ int v = off[i] + bsums[blockIdx.x]; off[i]=v; cur[i]=v; }
}
__global__ void k_fill(const int* __restrict__ dst, const int* __restrict__ src,
                       int* __restrict__ cur, int* __restrict__ perm,
                       int* __restrict__ srcP, int* __restrict__ nodeP){
  int e = blockIdx.x*256 + threadIdx.x;
  int d = dst[e];
  int pos = atomicAdd(&cur[d], 1);
  perm[e] = pos;
  srcP[pos] = src[e];
  nodeP[pos] = d;
}
__global__ void k_prev(const int* __restrict__ rev, const int* __restrict__ perm, int* __restrict__ prevP){
  int e = blockIdx.x*256 + threadIdx.x;
  prevP[perm[e]] = perm[rev[e]];
}

// ---------------- final: relu(e2n)@Wo+bo -> relu -> graph segsum ----------------
__global__ __launch_bounds__(256) void k_final(const float* __restrict__ e2n, const float* __restrict__ Wo,
                                               const float* __restrict__ bo, const int* __restrict__ gid,
                                               float* __restrict__ yacc){
  __shared__ float w[D*D];
  for (int i=threadIdx.x;i<D*D;i+=256) w[i]=Wo[i];
  __syncthreads();
  const int d = threadIdx.x&63, sub = threadIdx.x>>6;
  const int n0 = blockIdx.x*32 + sub*8;
  const float bod = bo[d];
  float acc=0.f; int curg=-1;
  for (int i=0;i<8;i++){
    int n=n0+i;
    if (n>=NN) break;
    int g = gid[n];
    if (g!=curg){ if (curg>=0) atomicAdd(&yacc[curg*D+d], acc); curg=g; acc=0.f; }
    float v=bod;
    const float* er = e2n + (size_t)n*D;
    #pragma unroll 8
    for (int k=0;k<D;k++){ float h=er[k]; h = h>0.f?h:0.f; v += h*w[k*D+d]; }
    acc += (v>0.f ? v : 0.f);
  }
  if (curg>=0) atomicAdd(&yacc[curg*D+d], acc);
}
__global__ void k_out(const float* __restrict__ yacc, float* __restrict__ outp){
  int i = blockIdx.x*256 + threadIdx.x;
  if (i<NG*D){ float v=yacc[i]; outp[i]= v>0.f?v:0.f; }
}

// ---------------- workspace layout ----------------
static constexpr size_t SZ_E   = (size_t)NE*D*2;          // 102.4 MB bf16 edge array
static constexpr size_t SZ_NF4 = (size_t)NN*D*4;          // 12.8 MB fp32 node array
static constexpr size_t SZ_NB  = (size_t)NN*D*2;          // 6.4 MB bf16 node array
static constexpr size_t OFF_IMP  = 0;
static constexpr size_t OFF_CPA  = SZ_E;
static constexpr size_t OFF_CPB  = 2*SZ_E;
static constexpr size_t OFF_NA0  = 3*SZ_E;
static constexpr size_t OFF_NA1  = OFF_NA0 + SZ_NF4;
static constexpr size_t OFF_E2N  = OFF_NA1 + SZ_NF4;
static constexpr size_t OFF_INL  = OFF_E2N + SZ_NF4;      // bf16 node linear
static constexpr size_t OFF_COFF = OFF_INL + SZ_NB;
static constexpr size_t OFF_CCUR = OFF_COFF + 200064;
static constexpr size_t OFF_PERM = OFF_CCUR + 200064;
static constexpr size_t OFF_SRCP = OFF_PERM + (size_t)NE*4;
static constexpr size_t OFF_PRVP = OFF_SRCP + (size_t)NE*4;
static constexpr size_t OFF_NODP = OFF_PRVP + (size_t)NE*4;
static constexpr size_t OFF_BS   = OFF_NODP + (size_t)NE*4;
static constexpr size_t OFF_YACC = OFF_BS + 256;

extern "C" void kernel_launch(void* const* d_in, const int* in_sizes, int n_in,
                              void* d_out, int out_size, void* d_ws, size_t ws_size,
                              hipStream_t stream) {
  const float* node_feat = (const float*)d_in[0];
  const float* edge_feat = (const float*)d_in[1];
  const int*   src       = (const int*)d_in[2];
  const int*   dst       = (const int*)d_in[3];
  const int*   rev       = (const int*)d_in[4];
  const int*   gid       = (const int*)d_in[5];
  const float* Wn = (const float*)d_in[7];
  const float* bn = (const float*)d_in[8];
  const float* We = (const float*)d_in[9];
  const float* be = (const float*)d_in[10];
  const float* Wc = (const float*)d_in[11];
  const float* bc = (const float*)d_in[12];
  const float* Wo = (const float*)d_in[13];
  const float* bo = (const float*)d_in[14];

  char* ws = (char*)d_ws;
  u16*   imP     = (u16*)(ws + OFF_IMP);
  u16*   curPA   = (u16*)(ws + OFF_CPA);
  u16*   curPB   = (u16*)(ws + OFF_CPB);
  float* naW0    = (float*)(ws + OFF_NA0);
  float* naW1    = (float*)(ws + OFF_NA1);
  float* e2n     = (float*)(ws + OFF_E2N);
  u16*   inlb    = (u16*)(ws + OFF_INL);
  int*   csr_off = (int*)(ws + OFF_COFF);
  int*   csr_cur = (int*)(ws + OFF_CCUR);
  int*   perm    = (int*)(ws + OFF_PERM);
  int*   srcP    = (int*)(ws + OFF_SRCP);
  int*   prevP   = (int*)(ws + OFF_PRVP);
  int*   nodeP   = (int*)(ws + OFF_NODP);
  int*   bsums   = (int*)(ws + OFF_BS);
  float* yacc    = (float*)(ws + OFF_YACC);

  hipMemsetAsync(csr_cur, 0, NN*sizeof(int), stream);
  hipMemsetAsync(yacc, 0, NG*D*sizeof(float), stream);

  // CSR build: offsets + perm + permuted index arrays
  k_hist <<<NE/256, 256, 0, stream>>>(dst, csr_cur);
  k_scan1<<<49, 1024, 0, stream>>>(csr_cur, csr_off, bsums, NN);
  k_scan2<<<1, 64, 0, stream>>>(bsums, 49, csr_off + NN);
  k_scan3<<<49, 1024, 0, stream>>>(csr_off, csr_cur, bsums, NN);
  k_fill <<<NE/256, 256, 0, stream>>>(dst, src, csr_cur, perm, srcP, nodeP);
  k_prev <<<NE/256, 256, 0, stream>>>(rev, perm, prevP);

  // front end
  k_inl<<<NN/4, 256, 0, stream>>>(node_feat, Wn, bn, inlb);
  k_im <<<NE/64, 256, 0, stream>>>(edge_feat, We, be, inlb, src, perm, imP);

  // loopy BP with fused per-node reduction (stream-serialized memset/launch order)
  hipMemsetAsync(naW0, 0, SZ_NF4, stream);
  k_iter<0><<<NE/64, 256, 0, stream>>>(imP, curPA, naW0, Wc, bc, srcP, prevP, nodeP, curPA, naW0);
  hipMemsetAsync(naW1, 0, SZ_NF4, stream);
  k_iter<1><<<NE/64, 256, 0, stream>>>(imP, curPA, naW0, Wc, bc, srcP, prevP, nodeP, curPB, naW1);
  hipMemsetAsync(naW0, 0, SZ_NF4, stream);
  k_iter<1><<<NE/64, 256, 0, stream>>>(imP, curPB, naW1, Wc, bc, srcP, prevP, nodeP, curPA, naW0);
  hipMemsetAsync(e2n, 0, SZ_NF4, stream);
  k_last<<<NE/64, 256, 0, stream>>>(imP, curPA, naW0, bc, srcP, prevP, nodeP, e2n);

  // head
  k_final<<<(NN+31)/32, 256, 0, stream>>>(e2n, Wo, bo, gid, yacc);
  k_out<<<(NG*D)/256, 256, 0, stream>>>(yacc, (float*)d_out);
}

// Round 6
// 710.258 us; speedup vs baseline: 1.1818x; 1.0077x over previous
//
#include <hip/hip_runtime.h>

// EmbedLoopyBP on gfx950 — round 6.
// R5 + gather->scatter swap: prevP is an involution, and fused segsum means
// the only consumer of curW is the reverse-edge lookup. k_iter now WRITES
// scatter (revOut[prevP[slot]] = row) and the next kernel READS sequentially
// (revIn[slot]). All k_iter/k_last reads are streams; randomness lives only
// in fire-and-forget 128B-row scatter writes. Also removed the phase2->
// reduction barrier (wave-local os dependency).

#define NN 50000
#define NE 800000
#define NG 128
#define D 64
#define LDE 36
#define LDW 66
#define LDO 72

typedef unsigned short u16;
typedef unsigned int u32;
typedef __bf16 bf16x8 __attribute__((ext_vector_type(8)));
typedef float f32x4 __attribute__((ext_vector_type(4)));

__device__ __forceinline__ float b2f(u16 u){ u32 x=((u32)u)<<16; float f; __builtin_memcpy(&f,&x,4); return f; }
__device__ __forceinline__ u16 f2b(float f){ u32 x; __builtin_memcpy(&x,&f,4); x += 0x7fffu + ((x>>16)&1u); return (u16)(x>>16); }
__device__ __forceinline__ u32 pack2(float a, float b){ return (u32)f2b(a) | ((u32)f2b(b)<<16); }
__device__ __forceinline__ void unpack8(uint4 v, float* o){
  o[0]=b2f((u16)(v.x&0xffffu)); o[1]=b2f((u16)(v.x>>16));
  o[2]=b2f((u16)(v.y&0xffffu)); o[3]=b2f((u16)(v.y>>16));
  o[4]=b2f((u16)(v.z&0xffffu)); o[5]=b2f((u16)(v.z>>16));
  o[6]=b2f((u16)(v.w&0xffffu)); o[7]=b2f((u16)(v.w>>16));
}

// ---------------- node linear: inlb = bf16(node_feat @ Wn + bn) ----------------
__global__ __launch_bounds__(256) void k_inl(const float* __restrict__ nf, const float* __restrict__ Wn,
                                             const float* __restrict__ bn, u16* __restrict__ inlb){
  __shared__ float w[D*D];
  for (int i=threadIdx.x;i<D*D;i+=256) w[i]=Wn[i];
  __syncthreads();
  const int d = threadIdx.x&63;
  const int n = blockIdx.x*4 + (threadIdx.x>>6);
  if (n>=NN) return;
  float v = bn[d];
  const float* row = nf + (size_t)n*D;
  #pragma unroll 8
  for (int k=0;k<D;k++) v += row[k]*w[k*D+d];
  inlb[(size_t)n*D+d] = f2b(v);
}

// ---------------- imP[perm[e]] = edge_feat@We + be + inl[src[e]]  (bf16) ----------------
__global__ __launch_bounds__(256) void k_im(const float* __restrict__ ef, const float* __restrict__ We,
                                            const float* __restrict__ be, const u16* __restrict__ inlb,
                                            const int* __restrict__ src, const int* __restrict__ perm,
                                            u16* __restrict__ imP){
  __shared__ __align__(16) u16 efs[64*LDE];
  __shared__ __align__(16) u16 wts[64*LDE];
  __shared__ float os[64*68];
  const int t = threadIdx.x;
  const int ebase = blockIdx.x*64;
  { // stage We^T bf16 : wts[n][k], k<32
    int n=t&63, k0=(t>>6)*8;
    #pragma unroll
    for (int j=0;j<8;j++) wts[n*LDE + k0 + j] = f2b(We[(k0+j)*D + n]);
  }
  { // stage edge_feat bf16 (coalesced float4 reads)
    int e=t>>2, k0=(t&3)*8;
    const float* p = ef + (size_t)(ebase+e)*32 + k0;
    float4 v0=*(const float4*)p, v1=*(const float4*)(p+4);
    uint4 pk = make_uint4(pack2(v0.x,v0.y),pack2(v0.z,v0.w),pack2(v1.x,v1.y),pack2(v1.z,v1.w));
    *(uint4*)&efs[e*LDE + k0] = pk;
  }
  __syncthreads();
  { // MFMA 16x16x32 (K=32, one step)
    int w=t>>6, lane=t&63, q=lane>>4, mr=lane&15;
    int rowb=w*16;
    bf16x8 A = *(const bf16x8*)&efs[(rowb+mr)*LDE + q*8];
    #pragma unroll
    for (int nt=0;nt<4;nt++){
      bf16x8 B = *(const bf16x8*)&wts[(nt*16+mr)*LDE + q*8];
      f32x4 acc = {0.f,0.f,0.f,0.f};
      acc = __builtin_amdgcn_mfma_f32_16x16x32_bf16(A,B,acc,0,0,0);
      #pragma unroll
      for (int r=0;r<4;r++) os[(rowb+q*4+r)*68 + nt*16+mr] = acc[r];
    }
  }
  __syncthreads();
  { // epilogue: + be + inlb[src[e]] -> bf16, full-row scatter to imP[perm[e]]
    int e=t>>2, d0=(t&3)*16;
    const size_t eg = (size_t)(ebase+e);
    const int s = src[eg], ps = perm[eg];
    const u16* ip = inlb + (size_t)s*D + d0;
    uint4 iv0 = *(const uint4*)ip, iv1 = *(const uint4*)(ip+8);
    float il[16]; unpack8(iv0,il); unpack8(iv1,il+8);
    float x[16];
    #pragma unroll
    for (int j=0;j<16;j++) x[j] = os[e*68 + d0 + j] + be[d0+j] + il[j];
    uint4 p0 = make_uint4(pack2(x[0],x[1]),pack2(x[2],x[3]),pack2(x[4],x[5]),pack2(x[6],x[7]));
    uint4 p1 = make_uint4(pack2(x[8],x[9]),pack2(x[10],x[11]),pack2(x[12],x[13]),pack2(x[14],x[15]));
    u16* op = imP + (size_t)ps*D + d0;
    *(uint4*)op = p0; *(uint4*)(op+8) = p1;
  }
}

// ---------------- iteration kernel (slot order, all-stream reads) ----------------
// MODE 0: x=relu(imP[slot]);                              revOut[prevP[slot]]=(x@Wc); naW_out += per-node
// MODE 1: x=relu(naW_in[srcP]-revIn[slot]+bc+imP[slot]);  same outputs
template<int MODE>
__global__ __launch_bounds__(256) void k_iter(const u16* __restrict__ imP, const u16* __restrict__ revIn,
      const float* __restrict__ naW_in, const float* __restrict__ Wc, const float* __restrict__ bc,
      const int* __restrict__ srcP, const int* __restrict__ prevP, const int* __restrict__ nodeP,
      u16* __restrict__ revOut, float* __restrict__ naW_out){
  __shared__ __align__(16) u16 xs[64*LDW];
  __shared__ __align__(16) u16 wts[64*LDW];
  __shared__ __align__(16) u16 os[64*LDO];
  __shared__ int nid[64];
  const int t = threadIdx.x;
  const size_t sbase = (size_t)blockIdx.x*64;
  { // stage Wc^T bf16 : wts[n][k]
    int n=t&63, k0=(t>>6)*16;
    #pragma unroll
    for (int j=0;j<16;j++) wts[n*LDW + k0 + j] = f2b(Wc[(k0+j)*D + n]);
  }
  if (t < 64) nid[t] = nodeP[sbase + t];
  { // phase 1: elementwise, 4 threads per slot row — ALL sequential reads
    const int e = t>>2, d0 = (t&3)*16;
    const size_t slot = sbase + e;
    const u16* ip = imP + slot*D + d0;
    uint4 r0 = *(const uint4*)ip;
    uint4 r1 = *(const uint4*)(ip+8);
    float x[16];
    unpack8(r0, x); unpack8(r1, x+8);
    if (MODE == 1){
      const int sp = srcP[slot];
      const u16* cp = revIn + slot*D + d0;           // sequential stream now
      uint4 c0 = *(const uint4*)cp, c1 = *(const uint4*)(cp+8);
      const float* np_ = naW_in + (size_t)sp*D + d0;
      float4 a0=*(const float4*)np_,     a1=*(const float4*)(np_+4);
      float4 a2=*(const float4*)(np_+8), a3=*(const float4*)(np_+12);
      float nv[16] = {a0.x,a0.y,a0.z,a0.w, a1.x,a1.y,a1.z,a1.w,
                      a2.x,a2.y,a2.z,a2.w, a3.x,a3.y,a3.z,a3.w};
      float cv[16];
      unpack8(c0,cv); unpack8(c1,cv+8);
      #pragma unroll
      for (int j=0;j<16;j++) x[j] += nv[j] - cv[j] + bc[d0+j];
    }
    #pragma unroll
    for (int j=0;j<16;j++) x[j] = x[j]>0.f ? x[j] : 0.f;
    uint4 p0 = make_uint4(pack2(x[0],x[1]),pack2(x[2],x[3]),pack2(x[4],x[5]),pack2(x[6],x[7]));
    uint4 p1 = make_uint4(pack2(x[8],x[9]),pack2(x[10],x[11]),pack2(x[12],x[13]),pack2(x[14],x[15]));
    u16* q = &xs[e*LDW + d0];
    *(uint4*)q = p0; *(uint4*)(q+8) = p1;
  }
  __syncthreads();
  { // phase 2: x @ Wc via MFMA; scatter 16B row-stores to revOut[prevP[row]]
    const int w=t>>6, lane=t&63, q=lane>>4, mr=lane&15;
    const int rowb = w*16;
    bf16x8 A0 = *(const bf16x8*)&xs[(rowb+mr)*LDW + q*8];
    bf16x8 A1 = *(const bf16x8*)&xs[(rowb+mr)*LDW + 32 + q*8];
    #pragma unroll
    for (int nt=0;nt<4;nt++){
      bf16x8 B0 = *(const bf16x8*)&wts[(nt*16+mr)*LDW + q*8];
      bf16x8 B1 = *(const bf16x8*)&wts[(nt*16+mr)*LDW + 32 + q*8];
      f32x4 acc = {0.f,0.f,0.f,0.f};
      acc = __builtin_amdgcn_mfma_f32_16x16x32_bf16(A0,B0,acc,0,0,0);
      acc = __builtin_amdgcn_mfma_f32_16x16x32_bf16(A1,B1,acc,0,0,0);
      #pragma unroll
      for (int r=0;r<4;r++) os[(rowb+q*4+r)*LDO + nt*16 + mr] = f2b(acc[r]);
    }
    const int lr = lane>>2, cc = lane&3;
    const int tgt = prevP[sbase + rowb + lr];        // bijective scatter target
    u16* gp = revOut + (size_t)tgt*D + cc*16;
    *(uint4*)gp     = *(const uint4*)&os[(rowb+lr)*LDO + cc*16];
    *(uint4*)(gp+8) = *(const uint4*)&os[(rowb+lr)*LDO + cc*16 + 8];
    // fused segment sum: wave w reduces exactly the os rows it wrote (wave-local,
    // no barrier needed); lane = column
    const int d = lane;
    float acc = 0.f;
    int curn = nid[rowb];
    #pragma unroll 4
    for (int r = rowb; r < rowb+16; ++r){
      int n = nid[r];                                // wave-uniform
      if (n != curn){
        atomicAdd(&naW_out[(size_t)curn*D + d], acc);
        curn = n; acc = 0.f;
      }
      acc += b2f(os[r*LDO + d]);
    }
    atomicAdd(&naW_out[(size_t)curn*D + d], acc);
  }
}

// ---------------- final BP step: x only (no matmul); e2n += per-node ----------------
__global__ __launch_bounds__(256) void k_last(const u16* __restrict__ imP, const u16* __restrict__ revIn,
      const float* __restrict__ naW_in, const float* __restrict__ bc,
      const int* __restrict__ srcP, const int* __restrict__ nodeP,
      float* __restrict__ e2n){
  __shared__ __align__(16) u16 xs[64*LDW];
  __shared__ int nid[64];
  const int t = threadIdx.x;
  const size_t sbase = (size_t)blockIdx.x*64;
  if (t < 64) nid[t] = nodeP[sbase + t];
  {
    const int e = t>>2, d0 = (t&3)*16;
    const size_t slot = sbase + e;
    const u16* ip = imP + slot*D + d0;
    uint4 r0 = *(const uint4*)ip, r1 = *(const uint4*)(ip+8);
    float x[16];
    unpack8(r0, x); unpack8(r1, x+8);
    const int sp = srcP[slot];
    const u16* cp = revIn + slot*D + d0;             // sequential
    uint4 c0 = *(const uint4*)cp, c1 = *(const uint4*)(cp+8);
    const float* np_ = naW_in + (size_t)sp*D + d0;
    float4 a0=*(const float4*)np_,     a1=*(const float4*)(np_+4);
    float4 a2=*(const float4*)(np_+8), a3=*(const float4*)(np_+12);
    float nv[16] = {a0.x,a0.y,a0.z,a0.w, a1.x,a1.y,a1.z,a1.w,
                    a2.x,a2.y,a2.z,a2.w, a3.x,a3.y,a3.z,a3.w};
    float cv[16];
    unpack8(c0,cv); unpack8(c1,cv+8);
    #pragma unroll
    for (int j=0;j<16;j++){ x[j] += nv[j] - cv[j] + bc[d0+j]; x[j] = x[j]>0.f ? x[j] : 0.f; }
    uint4 p0 = make_uint4(pack2(x[0],x[1]),pack2(x[2],x[3]),pack2(x[4],x[5]),pack2(x[6],x[7]));
    uint4 p1 = make_uint4(pack2(x[8],x[9]),pack2(x[10],x[11]),pack2(x[12],x[13]),pack2(x[14],x[15]));
    u16* q = &xs[e*LDW + d0];
    *(uint4*)q = p0; *(uint4*)(q+8) = p1;
  }
  __syncthreads();
  {
    const int d = t&63, g = t>>6;
    float acc = 0.f;
    int curn = nid[g*16];
    #pragma unroll 4
    for (int r = g*16; r < g*16+16; ++r){
      int n = nid[r];
      if (n != curn){
        atomicAdd(&e2n[(size_t)curn*D + d], acc);
        curn = n; acc = 0.f;
      }
      acc += b2f(xs[r*LDW + d]);
    }
    atomicAdd(&e2n[(size_t)curn*D + d], acc);
  }
}

// ---------------- CSR build ----------------
__global__ void k_hist(const int* __restrict__ dst, int* __restrict__ cnt){
  int e = blockIdx.x*256 + threadIdx.x;
  atomicAdd(&cnt[dst[e]], 1);
}
__global__ __launch_bounds__(1024) void k_scan1(const int* __restrict__ cnt, int* __restrict__ outv,
                                                int* __restrict__ bsums, int n){
  __shared__ int sh[1024];
  int i = blockIdx.x*1024 + threadIdx.x;
  int v = (i<n)? cnt[i] : 0;
  sh[threadIdx.x]=v;
  __syncthreads();
  for (int off=1; off<1024; off<<=1){
    int tv = (threadIdx.x>=(unsigned)off)? sh[threadIdx.x-off] : 0;
    __syncthreads();
    sh[threadIdx.x] += tv;
    __syncthreads();
  }
  if (i<n) outv[i] = sh[threadIdx.x] - v;
  if (threadIdx.x==1023) bsums[blockIdx.x] = sh[1023];
}
__global__ void k_scan2(int* bsums, int nb, int* tot){
  if (threadIdx.x==0 && blockIdx.x==0){
    int run=0;
    for (int b=0;b<nb;b++){ int v=bsums[b]; bsums[b]=run; run+=v; }
    *tot = run;
  }
}
__global__ __launch_bounds__(1024) void k_scan3(int* __restrict__ off, int* __restrict__ cur,
                                                const int* __restrict__ bsums, int n){
  int i = blockIdx.x*1024 + threadIdx.x;
  if (i<n){ int v = off[i] + bsums[blockIdx.x]; off[i]=v; cur[i]=v; }
}
__global__ void k_fill(const int* __restrict__ dst, const int* __restrict__ src,
                       int* __restrict__ cur, int* __restrict__ perm,
                       int* __restrict__ srcP, int* __restrict__ nodeP){
  int e = blockIdx.x*256 + threadIdx.x;
  int d = dst[e];
  int pos = atomicAdd(&cur[d], 1);
  perm[e] = pos;
  srcP[pos] = src[e];
  nodeP[pos] = d;
}
__global__ void k_prev(const int* __restrict__ rev, const int* __restrict__ perm, int* __restrict__ prevP){
  int e = blockIdx.x*256 + threadIdx.x;
  prevP[perm[e]] = perm[rev[e]];
}

// ---------------- final: relu(e2n)@Wo+bo -> relu -> graph segsum ----------------
__global__ __launch_bounds__(256) void k_final(const float* __restrict__ e2n, const float* __restrict__ Wo,
                                               const float* __restrict__ bo, const int* __restrict__ gid,
                                               float* __restrict__ yacc){
  __shared__ float w[D*D];
  for (int i=threadIdx.x;i<D*D;i+=256) w[i]=Wo[i];
  __syncthreads();
  const int d = threadIdx.x&63, sub = threadIdx.x>>6;
  const int n0 = blockIdx.x*32 + sub*8;
  const float bod = bo[d];
  float acc=0.f; int curg=-1;
  for (int i=0;i<8;i++){
    int n=n0+i;
    if (n>=NN) break;
    int g = gid[n];
    if (g!=curg){ if (curg>=0) atomicAdd(&yacc[curg*D+d], acc); curg=g; acc=0.f; }
    float v=bod;
    const float* er = e2n + (size_t)n*D;
    #pragma unroll 8
    for (int k=0;k<D;k++){ float h=er[k]; h = h>0.f?h:0.f; v += h*w[k*D+d]; }
    acc += (v>0.f ? v : 0.f);
  }
  if (curg>=0) atomicAdd(&yacc[curg*D+d], acc);
}
__global__ void k_out(const float* __restrict__ yacc, float* __restrict__ outp){
  int i = blockIdx.x*256 + threadIdx.x;
  if (i<NG*D){ float v=yacc[i]; outp[i]= v>0.f?v:0.f; }
}

// ---------------- workspace layout ----------------
static constexpr size_t SZ_E   = (size_t)NE*D*2;          // 102.4 MB bf16 edge array
static constexpr size_t SZ_NF4 = (size_t)NN*D*4;          // 12.8 MB fp32 node array
static constexpr size_t SZ_NB  = (size_t)NN*D*2;          // 6.4 MB bf16 node array
static constexpr size_t OFF_IMP  = 0;
static constexpr size_t OFF_RVA  = SZ_E;
static constexpr size_t OFF_RVB  = 2*SZ_E;
static constexpr size_t OFF_NA0  = 3*SZ_E;
static constexpr size_t OFF_NA1  = OFF_NA0 + SZ_NF4;
static constexpr size_t OFF_E2N  = OFF_NA1 + SZ_NF4;
static constexpr size_t OFF_INL  = OFF_E2N + SZ_NF4;      // bf16 node linear
static constexpr size_t OFF_COFF = OFF_INL + SZ_NB;
static constexpr size_t OFF_CCUR = OFF_COFF + 200064;
static constexpr size_t OFF_PERM = OFF_CCUR + 200064;
static constexpr size_t OFF_SRCP = OFF_PERM + (size_t)NE*4;
static constexpr size_t OFF_PRVP = OFF_SRCP + (size_t)NE*4;
static constexpr size_t OFF_NODP = OFF_PRVP + (size_t)NE*4;
static constexpr size_t OFF_BS   = OFF_NODP + (size_t)NE*4;
static constexpr size_t OFF_YACC = OFF_BS + 256;

extern "C" void kernel_launch(void* const* d_in, const int* in_sizes, int n_in,
                              void* d_out, int out_size, void* d_ws, size_t ws_size,
                              hipStream_t stream) {
  const float* node_feat = (const float*)d_in[0];
  const float* edge_feat = (const float*)d_in[1];
  const int*   src       = (const int*)d_in[2];
  const int*   dst       = (const int*)d_in[3];
  const int*   rev       = (const int*)d_in[4];
  const int*   gid       = (const int*)d_in[5];
  const float* Wn = (const float*)d_in[7];
  const float* bn = (const float*)d_in[8];
  const float* We = (const float*)d_in[9];
  const float* be = (const float*)d_in[10];
  const float* Wc = (const float*)d_in[11];
  const float* bc = (const float*)d_in[12];
  const float* Wo = (const float*)d_in[13];
  const float* bo = (const float*)d_in[14];

  char* ws = (char*)d_ws;
  u16*   imP     = (u16*)(ws + OFF_IMP);
  u16*   revA    = (u16*)(ws + OFF_RVA);
  u16*   revB    = (u16*)(ws + OFF_RVB);
  float* naW0    = (float*)(ws + OFF_NA0);
  float* naW1    = (float*)(ws + OFF_NA1);
  float* e2n     = (float*)(ws + OFF_E2N);
  u16*   inlb    = (u16*)(ws + OFF_INL);
  int*   csr_off = (int*)(ws + OFF_COFF);
  int*   csr_cur = (int*)(ws + OFF_CCUR);
  int*   perm    = (int*)(ws + OFF_PERM);
  int*   srcP    = (int*)(ws + OFF_SRCP);
  int*   prevP   = (int*)(ws + OFF_PRVP);
  int*   nodeP   = (int*)(ws + OFF_NODP);
  int*   bsums   = (int*)(ws + OFF_BS);
  float* yacc    = (float*)(ws + OFF_YACC);

  hipMemsetAsync(csr_cur, 0, NN*sizeof(int), stream);
  hipMemsetAsync(yacc, 0, NG*D*sizeof(float), stream);

  // CSR build: offsets + perm + permuted index arrays
  k_hist <<<NE/256, 256, 0, stream>>>(dst, csr_cur);
  k_scan1<<<49, 1024, 0, stream>>>(csr_cur, csr_off, bsums, NN);
  k_scan2<<<1, 64, 0, stream>>>(bsums, 49, csr_off + NN);
  k_scan3<<<49, 1024, 0, stream>>>(csr_off, csr_cur, bsums, NN);
  k_fill <<<NE/256, 256, 0, stream>>>(dst, src, csr_cur, perm, srcP, nodeP);
  k_prev <<<NE/256, 256, 0, stream>>>(rev, perm, prevP);

  // front end
  k_inl<<<NN/4, 256, 0, stream>>>(node_feat, Wn, bn, inlb);
  k_im <<<NE/64, 256, 0, stream>>>(edge_feat, We, be, inlb, src, perm, imP);

  // loopy BP: scatter-write rev buffers, stream-read everything
  hipMemsetAsync(naW0, 0, SZ_NF4, stream);
  k_iter<0><<<NE/64, 256, 0, stream>>>(imP, revA, naW0, Wc, bc, srcP, prevP, nodeP, revA, naW0);
  hipMemsetAsync(naW1, 0, SZ_NF4, stream);
  k_iter<1><<<NE/64, 256, 0, stream>>>(imP, revA, naW0, Wc, bc, srcP, prevP, nodeP, revB, naW1);
  hipMemsetAsync(naW0, 0, SZ_NF4, stream);
  k_iter<1><<<NE/64, 256, 0, stream>>>(imP, revB, naW1, Wc, bc, srcP, prevP, nodeP, revA, naW0);
  hipMemsetAsync(e2n, 0, SZ_NF4, stream);
  k_last<<<NE/64, 256, 0, stream>>>(imP, revA, naW0, bc, srcP, nodeP, e2n);

  // head
  k_final<<<(NN+31)/32, 256, 0, stream>>>(e2n, Wo, bo, gid, yacc);
  k_out<<<(NG*D)/256, 256, 0, stream>>>(yacc, (float*)d_out);
}